// Round 1
// baseline (155.154 us; speedup 1.0000x reference)
//
#include <hip/hip_runtime.h>

#ifndef __has_builtin
#define __has_builtin(x) 0
#endif

#if __has_builtin(__builtin_amdgcn_exp2f)
#define EXP2F(x) __builtin_amdgcn_exp2f(x)
#else
#define EXP2F(x) exp2f(x)
#endif

#if __has_builtin(__builtin_amdgcn_rcpf)
#define RCPF(x) __builtin_amdgcn_rcpf(x)
#else
#define RCPF(x) (1.0f / (x))
#endif

namespace {

constexpr int kB = 65536;
constexpr int kT = 50;
constexpr int kI = 2;
constexpr int kH = 20;
constexpr int kO = 2;

__device__ __forceinline__ float fast_tanh(float v) {
    // tanh(v) = 1 - 2/(exp(2v)+1);  exp(2v) = exp2(v * 2*log2(e))
    // v_exp_f32 saturates: +inf -> 1, 0 -> -1, so no range clamping needed.
    const float p = EXP2F(v * 2.8853900817779268f);
    return fmaf(-2.0f, RCPF(p + 1.0f), 1.0f);
}

// 4 threads per batch element. Thread sub (= lane&3) owns hidden rows
// h = 4*i + sub, i = 0..4.  W_hh kept entirely in registers, column order
// permuted per-thread so the shuffle-gathered h values line up with
// compile-time register indices:
//   w[i][r][d] = W_hh[(4i+sub)*20 + (4r + (sub^d))]
//   v_d        = __shfl_xor(h_own[r], d)  ==  h_{4r + (sub^d)}
__global__ __launch_bounds__(256, 2) void dprnn_kernel(
    const float* __restrict__ x, const float* __restrict__ W_ih,
    const float* __restrict__ W_hh, const float* __restrict__ b_ih,
    const float* __restrict__ b_hh, const float* __restrict__ W_out,
    const float* __restrict__ b_out, const float* __restrict__ mask,
    float* __restrict__ out)
{
    const int tid = blockIdx.x * 256 + threadIdx.x;
    const int g   = tid >> 2;   // batch element
    const int sub = tid & 3;    // quarter of H owned

    float w[5][5][4];
    float wi0[5], wi1[5], bia[5], wo0[5], wo1[5];
#pragma unroll
    for (int i = 0; i < 5; ++i) {
        const int row = 4 * i + sub;
#pragma unroll
        for (int r = 0; r < 5; ++r) {
#pragma unroll
            for (int d = 0; d < 4; ++d) {
                w[i][r][d] = W_hh[row * kH + 4 * r + (sub ^ d)];
            }
        }
        wi0[i] = W_ih[row * kI + 0];
        wi1[i] = W_ih[row * kI + 1];
        bia[i] = b_ih[row] + b_hh[row];
        wo0[i] = W_out[0 * kH + row];
        wo1[i] = W_out[1 * kH + row];
    }
    const float bo0 = b_out[0];
    const float bo1 = b_out[1];

    float h[5] = {0.f, 0.f, 0.f, 0.f, 0.f};

    const float* xp = x    + (size_t)g * (kT * kI);
    const float* mp = mask + (size_t)g * (kT * kH) + sub;
    float*       op = out  + (size_t)g * (kT * kO);

    // prefetch t = 0
    float2 xv = *reinterpret_cast<const float2*>(xp);
    float m[5];
#pragma unroll
    for (int r = 0; r < 5; ++r) m[r] = mp[4 * r];

    for (int t = 0; t < kT; ++t) {
        // issue next iteration's loads early (clamped re-load on last iter)
        const int tn = (t + 1 < kT) ? (t + 1) : t;
        const float2 xv_n = *reinterpret_cast<const float2*>(xp + tn * kI);
        const float* mq = mp + tn * kH;
        float n[5];
#pragma unroll
        for (int r = 0; r < 5; ++r) n[r] = mq[4 * r];

        // acc[i] = b_ih + b_hh + W_ih x_t  (for row 4i+sub)
        float acc[5];
#pragma unroll
        for (int i = 0; i < 5; ++i)
            acc[i] = fmaf(wi0[i], xv.x, fmaf(wi1[i], xv.y, bia[i]));

        // acc[i] += sum_j W_hh[row_i][j] * h_j   (h gathered via 4-lane shfl)
#pragma unroll
        for (int r = 0; r < 5; ++r) {
            const float v0 = h[r];
            const float v1 = __shfl_xor(h[r], 1);
            const float v2 = __shfl_xor(h[r], 2);
            const float v3 = __shfl_xor(h[r], 3);
#pragma unroll
            for (int i = 0; i < 5; ++i) {
                acc[i] = fmaf(w[i][r][0], v0, acc[i]);
                acc[i] = fmaf(w[i][r][1], v1, acc[i]);
                acc[i] = fmaf(w[i][r][2], v2, acc[i]);
                acc[i] = fmaf(w[i][r][3], v3, acc[i]);
            }
        }

        // h_new = tanh(acc); fused dropout + output projection partials
        float p0 = 0.f, p1 = 0.f;
#pragma unroll
        for (int i = 0; i < 5; ++i) {
            const float hn = fast_tanh(acc[i]);
            h[i] = hn;
            const float dm = hn * m[i];
            p0 = fmaf(dm, wo0[i], p0);
            p1 = fmaf(dm, wo1[i], p1);
        }
        // reduce partial output over the 4-lane group
        p0 += __shfl_xor(p0, 1);
        p0 += __shfl_xor(p0, 2);
        p1 += __shfl_xor(p1, 1);
        p1 += __shfl_xor(p1, 2);
        if (sub == 0) {
            *reinterpret_cast<float2*>(op + t * kO) =
                make_float2(p0 + bo0, p1 + bo1);
        }

        xv = xv_n;
#pragma unroll
        for (int r = 0; r < 5; ++r) m[r] = n[r];
    }
}

}  // namespace

extern "C" void kernel_launch(void* const* d_in, const int* in_sizes, int n_in,
                              void* d_out, int out_size, void* d_ws, size_t ws_size,
                              hipStream_t stream) {
    const float* x     = (const float*)d_in[0];
    const float* W_ih  = (const float*)d_in[1];
    const float* W_hh  = (const float*)d_in[2];
    const float* b_ih  = (const float*)d_in[3];
    const float* b_hh  = (const float*)d_in[4];
    const float* W_out = (const float*)d_in[5];
    const float* b_out = (const float*)d_in[6];
    const float* mask  = (const float*)d_in[7];
    float* out = (float*)d_out;

    const int threads = kB * 4;          // 262144
    dim3 block(256);
    dim3 grid(threads / 256);            // 1024 blocks, no tail
    dprnn_kernel<<<grid, block, 0, stream>>>(x, W_ih, W_hh, b_ih, b_hh,
                                             W_out, b_out, mask, out);
}

// Round 2
// 87.368 us; speedup vs baseline: 1.7759x; 1.7759x over previous
//
#include <hip/hip_runtime.h>

#ifndef __has_builtin
#define __has_builtin(x) 0
#endif

#if __has_builtin(__builtin_amdgcn_exp2f)
#define EXP2F(x) __builtin_amdgcn_exp2f(x)
#else
#define EXP2F(x) exp2f(x)
#endif

#if __has_builtin(__builtin_amdgcn_rcpf)
#define RCPF(x) __builtin_amdgcn_rcpf(x)
#else
#define RCPF(x) (1.0f / (x))
#endif

namespace {

constexpr int kB = 65536;
constexpr int kT = 50;
constexpr int kI = 2;
constexpr int kH = 20;
constexpr int kO = 2;

__device__ __forceinline__ float fast_tanh(float v) {
    // tanh(v) = 1 - 2/(exp(2v)+1);  exp(2v) = exp2(v * 2*log2(e))
    const float p = EXP2F(v * 2.8853900817779268f);
    return fmaf(-2.0f, RCPF(p + 1.0f), 1.0f);
}

// Intra-quad lane exchange via DPP quad_perm (pure VALU, no DS latency).
// dest lane i reads src lane perm[i] within its quad.
// xor1: [1,0,3,2]=0xB1  xor2: [2,3,0,1]=0x4E  xor3: [3,2,1,0]=0x1B
#if __has_builtin(__builtin_amdgcn_mov_dpp)
template <int CTRL>
__device__ __forceinline__ float fqp(float v) {
    return __int_as_float(
        __builtin_amdgcn_mov_dpp(__float_as_int(v), CTRL, 0xF, 0xF, true));
}
#else
template <int CTRL>
__device__ __forceinline__ float fqp(float v) {
    constexpr int d = (CTRL == 0xB1) ? 1 : (CTRL == 0x4E) ? 2 : 3;
    return __shfl_xor(v, d);
}
#endif

// 4 threads per batch element; thread sub (= lane&3) owns hidden rows
// 4*i + sub.  W_hh in registers, columns permuted per-thread so DPP-gathered
// h values line up with compile-time indices:
//   w[i][r][d] = W_hh[(4i+sub)*20 + (4r + (sub^d))]
//   v_d        = quad_perm-xor(h_own[r], d) == h_{4r + (sub^d)}
__global__ __launch_bounds__(256)
__attribute__((amdgpu_waves_per_eu(2, 3)))
void dprnn_kernel(
    const float* __restrict__ x, const float* __restrict__ W_ih,
    const float* __restrict__ W_hh, const float* __restrict__ b_ih,
    const float* __restrict__ b_hh, const float* __restrict__ W_out,
    const float* __restrict__ b_out, const float* __restrict__ mask,
    float* __restrict__ out)
{
    const int tid = blockIdx.x * 256 + threadIdx.x;
    const int g   = tid >> 2;            // batch element
    const int sub = tid & 3;             // quarter of H owned
    const int gl  = threadIdx.x >> 2;    // group index within block (0..63)

    __shared__ __align__(16) float lout[64 * kT * kO];  // 25.6 KB

    float w[5][5][4];
    float wi0[5], wi1[5], bia[5], wo0[5], wo1[5];
#pragma unroll
    for (int i = 0; i < 5; ++i) {
        const int row = 4 * i + sub;
#pragma unroll
        for (int r = 0; r < 5; ++r) {
#pragma unroll
            for (int d = 0; d < 4; ++d) {
                w[i][r][d] = W_hh[row * kH + 4 * r + (sub ^ d)];
            }
        }
        wi0[i] = W_ih[row * kI + 0];
        wi1[i] = W_ih[row * kI + 1];
        bia[i] = b_ih[row] + b_hh[row];
        wo0[i] = W_out[0 * kH + row];
        wo1[i] = W_out[1 * kH + row];
    }
    const float bo0 = b_out[0];
    const float bo1 = b_out[1];

    float h[5] = {0.f, 0.f, 0.f, 0.f, 0.f};

    const float* xp = x    + (size_t)g * (kT * kI);
    const float* mp = mask + (size_t)g * (kT * kH) + sub;

    // one RNN step; m = this step's dropout mask (rows 4r+sub), x0/x1 = x_t
    auto step = [&](const float m[5], float x0, float x1, int t) {
        float acc[5];
#pragma unroll
        for (int i = 0; i < 5; ++i)
            acc[i] = fmaf(wi0[i], x0, fmaf(wi1[i], x1, bia[i]));
#pragma unroll
        for (int r = 0; r < 5; ++r) {
            const float v0 = h[r];
            const float v1 = fqp<0xB1>(h[r]);
            const float v2 = fqp<0x4E>(h[r]);
            const float v3 = fqp<0x1B>(h[r]);
#pragma unroll
            for (int i = 0; i < 5; ++i) {
                acc[i] = fmaf(w[i][r][0], v0, acc[i]);
                acc[i] = fmaf(w[i][r][1], v1, acc[i]);
                acc[i] = fmaf(w[i][r][2], v2, acc[i]);
                acc[i] = fmaf(w[i][r][3], v3, acc[i]);
            }
        }
        float p0 = 0.f, p1 = 0.f;
#pragma unroll
        for (int i = 0; i < 5; ++i) {
            const float hn = fast_tanh(acc[i]);
            h[i] = hn;
            const float dm = hn * m[i];
            p0 = fmaf(dm, wo0[i], p0);
            p1 = fmaf(dm, wo1[i], p1);
        }
        p0 += fqp<0xB1>(p0);
        p0 += fqp<0x4E>(p0);
        p1 += fqp<0xB1>(p1);
        p1 += fqp<0x4E>(p1);
        if (sub == 0) {
            *reinterpret_cast<float2*>(&lout[gl * (kT * kO) + t * kO]) =
                make_float2(p0 + bo0, p1 + bo1);
        }
    };

    // prologue: load masks for t=0,1 and x for t=0,1
    float m0[5], m1[5];
#pragma unroll
    for (int r = 0; r < 5; ++r) m0[r] = mp[0 * kH + 4 * r];
#pragma unroll
    for (int r = 0; r < 5; ++r) m1[r] = mp[1 * kH + 4 * r];
    float4 xq = *reinterpret_cast<const float4*>(xp);

    // main: 24 blocks of 2 steps with distance-2 prefetch
    for (int tb = 0; tb < kT - 2; tb += 2) {
        float n0[5], n1[5];
        const float* mq = mp + (tb + 2) * kH;
#pragma unroll
        for (int r = 0; r < 5; ++r) n0[r] = mq[4 * r];
#pragma unroll
        for (int r = 0; r < 5; ++r) n1[r] = mq[kH + 4 * r];
        const float4 xq_n =
            *reinterpret_cast<const float4*>(xp + (tb + 2) * kI);

        step(m0, xq.x, xq.y, tb);
        step(m1, xq.z, xq.w, tb + 1);

#pragma unroll
        for (int r = 0; r < 5; ++r) { m0[r] = n0[r]; m1[r] = n1[r]; }
        xq = xq_n;
    }
    // tail: t = 48, 49 (no prefetch)
    step(m0, xq.x, xq.y, kT - 2);
    step(m1, xq.z, xq.w, kT - 1);

    // coalesced writeback of this block's 64*100 floats
    __syncthreads();
    const int k = threadIdx.x;
    float* ob = out + (size_t)blockIdx.x * (64 * kT * kO);
#pragma unroll
    for (int it = 0; it < 6; ++it) {
        const int idx = it * 1024 + k * 4;
        const float4 v = *reinterpret_cast<const float4*>(&lout[idx]);
        *reinterpret_cast<float4*>(ob + idx) = v;
    }
    {
        const int idx = 6144 + k;
        ob[idx] = lout[idx];
    }
}

}  // namespace

extern "C" void kernel_launch(void* const* d_in, const int* in_sizes, int n_in,
                              void* d_out, int out_size, void* d_ws, size_t ws_size,
                              hipStream_t stream) {
    const float* x     = (const float*)d_in[0];
    const float* W_ih  = (const float*)d_in[1];
    const float* W_hh  = (const float*)d_in[2];
    const float* b_ih  = (const float*)d_in[3];
    const float* b_hh  = (const float*)d_in[4];
    const float* W_out = (const float*)d_in[5];
    const float* b_out = (const float*)d_in[6];
    const float* mask  = (const float*)d_in[7];
    float* out = (float*)d_out;

    const int threads = kB * 4;          // 262144
    dim3 block(256);
    dim3 grid(threads / 256);            // 1024 blocks, no tail
    dprnn_kernel<<<grid, block, 0, stream>>>(x, W_ih, W_hh, b_ih, b_hh,
                                             W_out, b_out, mask, out);
}